// Round 7
// baseline (148.629 us; speedup 1.0000x reference)
//
#include <hip/hip_runtime.h>
#include <hip/hip_bf16.h>
#include <stdint.h>

#define OUTF 4096
#define INF  4096
#define MROWS 4096
#define GS 32

typedef __attribute__((ext_vector_type(8))) __bf16 bf16x8;
typedef __attribute__((ext_vector_type(4))) float f32x4;

__device__ inline void gload_lds16(const void* g, void* l) {
    __builtin_amdgcn_global_load_lds(
        (const __attribute__((address_space(1))) void*)g,
        (__attribute__((address_space(3))) void*)l, 16, 0, 0);
}

// Gather the 12 packed bytes of group `gid` (harness stores int8 input as
// sign-extended int32, 4B per packed byte).
__device__ inline void load_group_bits(const int* __restrict__ wq, int gid,
                                       uint64_t& lo, uint64_t& hi) {
    const int4* p = (const int4*)(wq + (size_t)gid * 12);
    int4 A = p[0], B = p[1], C = p[2];
    uint32_t d0 = (uint32_t)(A.x & 255) | ((uint32_t)(A.y & 255) << 8) |
                  ((uint32_t)(A.z & 255) << 16) | ((uint32_t)(A.w & 255) << 24);
    uint32_t d1 = (uint32_t)(B.x & 255) | ((uint32_t)(B.y & 255) << 8) |
                  ((uint32_t)(B.z & 255) << 16) | ((uint32_t)(B.w & 255) << 24);
    uint32_t d2 = (uint32_t)(C.x & 255) | ((uint32_t)(C.y & 255) << 8) |
                  ((uint32_t)(C.z & 255) << 16) | ((uint32_t)(C.w & 255) << 24);
    lo = (uint64_t)d0 | ((uint64_t)d1 << 32);
    hi = (uint64_t)d1 | ((uint64_t)d2 << 32);
}

// ---------------- fused prepass: x->bf16 (blocks 0..8191), W dequant (rest) --
__global__ void prep_kernel(const float* __restrict__ x, __bf16* __restrict__ xb,
                            const int* __restrict__ wq, const float* __restrict__ wn,
                            __bf16* __restrict__ wb) {
    const int bid = blockIdx.x;
    if (bid < 8192) {
        int i = bid * 256 + threadIdx.x;  // 2M threads, 8 floats each
        const f32x4* xp = (const f32x4*)x;
        f32x4 a = xp[2 * i], b = xp[2 * i + 1];
        bf16x8 v = { (__bf16)a[0], (__bf16)a[1], (__bf16)a[2], (__bf16)a[3],
                     (__bf16)b[0], (__bf16)b[1], (__bf16)b[2], (__bf16)b[3] };
        ((bf16x8*)xb)[i] = v;
    } else {
        int gid = (bid - 8192) * 256 + threadIdx.x;  // one 32-elem group
        uint64_t lo, hi;
        load_group_bits(wq, gid, lo, hi);
        float nrm = wn[gid];
        float c2 = nrm * (2.0f / 7.0f), c1 = -nrm;  // w = q*(2n/7) - n
        bf16x8 o[4];
#pragma unroll
        for (int j = 0; j < 32; ++j) {
            uint32_t q = (j <= 20) ? (uint32_t)((lo >> (3 * j)) & 7)
                                   : (uint32_t)((hi >> (3 * j - 32)) & 7);
            o[j >> 3][j & 7] = (__bf16)((float)q * c2 + c1);
        }
        bf16x8* outp = (bf16x8*)(wb + (size_t)gid * 32);
        outp[0] = o[0]; outp[1] = o[1]; outp[2] = o[2]; outp[3] = o[3];
    }
}

// ============ 256x256 GEMM, 4-phase counted-vmcnt, reg-dbuf operands =========
// BM=BN=256, BK=64, 512 threads (8 waves, 2Mx4N), mfma_f32_16x16x32_bf16.
// Quadrant walk q00->q10->q11->q01; each phase ds-reads exactly one new half
// (24 b128/wave/tile, the minimum). LDS 128KB [buf][A|B][half][128][64bf16],
// 16B-chunk XOR swizzle chunk^=row&7 (linear gload_lds dest, pre-swz source).
// Stage schedule at tile t (into buf t+1&1): A0'@P1 B0'@P2 A1'@P3 B1'@P4.
// VMCNT(4) at P1/P2/P4: each guarantees (vmcnt -> barrier -> read) the halves
// read next phase; >=4 loads (2 half-tiles) always in flight, never drain-0.

#define VMCNT(N) asm volatile("s_waitcnt vmcnt(" #N ")" ::: "memory")
#define BARR() do { asm volatile("" ::: "memory"); __builtin_amdgcn_s_barrier(); \
                    asm volatile("" ::: "memory"); } while (0)

#define RD_A(DST, RB, H) do { \
    _Pragma("unroll") \
    for (int m_ = 0; m_ < 4; ++m_) { \
        const int r_ = wr * 64 + m_ * 16 + row16; \
        _Pragma("unroll") \
        for (int kk_ = 0; kk_ < 2; ++kk_) \
            DST[m_][kk_] = *(const bf16x8*)(lds + (RB) * 65536 + (H) * 16384 + \
                r_ * 128 + (((kk_ * 4 + kq) * 16) ^ ((r_ & 7) << 4))); \
    } \
} while (0)

#define RD_B(DST, RB, H) do { \
    _Pragma("unroll") \
    for (int n_ = 0; n_ < 2; ++n_) { \
        const int r_ = wc * 32 + n_ * 16 + row16; \
        _Pragma("unroll") \
        for (int kk_ = 0; kk_ < 2; ++kk_) \
            DST[n_][kk_] = *(const bf16x8*)(lds + (RB) * 65536 + 32768 + (H) * 16384 + \
                r_ * 128 + (((kk_ * 4 + kq) * 16) ^ ((r_ & 7) << 4))); \
    } \
} while (0)

#define STAGE(SB, AB, H, SKT) do { \
    const __bf16* base_ = (AB) ? wb : xb; \
    const int brc_ = ((AB) ? bn : bm) * 256; \
    _Pragma("unroll") \
    for (int j_ = 0; j_ < 2; ++j_) \
        gload_lds16((const char*)(base_ + (size_t)(brc_ + (H) * 128 + j_ * 64 + srow) * INF + \
                                  (SKT) * 64 + schunk * 8), \
                    lds + (SB) * 65536 + (AB) * 32768 + (H) * 16384 + j_ * 8192 + tid * 16); \
} while (0)

#define MF_Q(A_, B_, MH, NH) do { \
    __builtin_amdgcn_s_setprio(1); \
    _Pragma("unroll") \
    for (int kk_ = 0; kk_ < 2; ++kk_) \
        _Pragma("unroll") \
        for (int m_ = 0; m_ < 4; ++m_) \
            _Pragma("unroll") \
            for (int n_ = 0; n_ < 2; ++n_) \
                acc[MH][NH][m_][n_] = __builtin_amdgcn_mfma_f32_16x16x32_bf16( \
                    A_[m_][kk_], B_[n_][kk_], acc[MH][NH][m_][n_], 0, 0, 0); \
    __builtin_amdgcn_s_setprio(0); \
} while (0)

__global__ __launch_bounds__(512, 2) void gemm8_kernel(
    const __bf16* __restrict__ xb, const __bf16* __restrict__ wb,
    const float* __restrict__ bias, float* __restrict__ out) {
    __shared__ __align__(16) unsigned char lds[131072];

    const int tid = threadIdx.x;
    const int lane = tid & 63, wid = tid >> 6;
    const int wr = wid >> 2, wc = wid & 3;
    const int row16 = lane & 15, kq = lane >> 4;

    // XCD-aware swizzle (256 wgs, 256%8==0 -> bijective)
    const int bid = blockIdx.x;
    const int wg = (bid & 7) * 32 + (bid >> 3);
    const int bn = wg & 15, bm = wg >> 4;

    // staging geometry: linear LDS dest, pre-swizzled global source chunk
    const int srow = tid >> 3;
    const int schunk = (tid & 7) ^ (srow & 7);

    f32x4 acc[2][2][4][2] = {};
    bf16x8 a0[4][2], a1[4][2], b0[2][2], b1[2][2];

    // prologue: stage tile 0 fully into buf0 (prologue-only full drain)
    STAGE(0, 0, 0, 0); STAGE(0, 1, 0, 0); STAGE(0, 0, 1, 0); STAGE(0, 1, 1, 0);
    VMCNT(0);
    BARR();

    for (int kt = 0; kt < INF / 64; ++kt) {
        const int rb = kt & 1, sb = rb ^ 1, nt = (kt + 1) & 63;
        // P1: q00 = A0 x B0
        STAGE(sb, 0, 0, nt);
        RD_A(a0, rb, 0); RD_B(b0, rb, 0);
        VMCNT(4);                 // drains A1(t),B0(t)-era loads; A1 safe for P2
        BARR();
        MF_Q(a0, b0, 0, 0);
        BARR();
        // P2: q10 = A1 x B0
        STAGE(sb, 1, 0, nt);
        RD_A(a1, rb, 1);
        VMCNT(4);                 // drains B1(t): safe for P3 read
        BARR();
        MF_Q(a1, b0, 1, 0);
        BARR();
        // P3: q11 = A1 x B1
        STAGE(sb, 0, 1, nt);
        RD_B(b1, rb, 1);
        BARR();
        MF_Q(a1, b1, 1, 1);
        BARR();
        // P4: q01 = A0 x B1
        STAGE(sb, 1, 1, nt);
        VMCNT(4);                 // drains A0',B0' of t+1: safe for t+1.P1
        BARR();
        MF_Q(a0, b1, 0, 1);
        BARR();
    }

    // epilogue: C = acc + bias (16x16 C layout: col=lane&15, row=kq*4+j)
#pragma unroll
    for (int nh = 0; nh < 2; ++nh)
#pragma unroll
        for (int n = 0; n < 2; ++n) {
            const int col = bn * 256 + nh * 128 + wc * 32 + n * 16 + row16;
            const float bv = bias[col];
#pragma unroll
            for (int mh = 0; mh < 2; ++mh)
#pragma unroll
                for (int m = 0; m < 4; ++m) {
                    const int rbase = bm * 256 + mh * 128 + wr * 64 + m * 16 + kq * 4;
#pragma unroll
                    for (int j = 0; j < 4; ++j)
                        out[(size_t)(rbase + j) * OUTF + col] = acc[mh][nh][m][n][j] + bv;
                }
        }
}

// ---------------- fallback (no workspace): fused 128^2 kernel ----------------
__global__ __launch_bounds__(256, 2) void gemm_fb_kernel(
    const float* __restrict__ x, const int* __restrict__ wq,
    const float* __restrict__ wn, const float* __restrict__ bias,
    float* __restrict__ out) {
    __shared__ __align__(16) unsigned char lAraw[128 * 128];
    __shared__ __align__(16) unsigned char lBraw[128 * 128];

    const int tid = threadIdx.x;
    const int lane = tid & 63, wid = tid >> 6;
    const int wr = wid >> 1, wc = wid & 1;
    const int bn = blockIdx.x, bm = blockIdx.y;
    const int row16 = lane & 15, kq = lane >> 4;

    f32x4 acc[4][4] = {};

    int aoff[4], boff[4];
#pragma unroll
    for (int m = 0; m < 4; ++m) {
        int r = wr * 64 + m * 16 + row16;
        aoff[m] = r * 128 + ((kq * 16) ^ ((r & 7) << 4));
    }
#pragma unroll
    for (int n = 0; n < 4; ++n) {
        int r = wc * 64 + n * 16 + row16;
        boff[n] = r * 128 + ((kq * 16) ^ ((r & 7) << 4));
    }

    for (int kt = 0; kt < INF / 64; ++kt) {
        __syncthreads();
#pragma unroll
        for (int it = 0; it < 4; ++it) {
            int row = it * 32 + (tid >> 3), c = tid & 7;
            const f32x4* xp = (const f32x4*)(x + (size_t)(bm * 128 + row) * INF + kt * 64 + c * 8);
            f32x4 a0 = xp[0], a1 = xp[1];
            bf16x8 v = { (__bf16)a0[0], (__bf16)a0[1], (__bf16)a0[2], (__bf16)a0[3],
                         (__bf16)a1[0], (__bf16)a1[1], (__bf16)a1[2], (__bf16)a1[3] };
            *(bf16x8*)(lAraw + row * 128 + ((c * 16) ^ ((row & 7) << 4))) = v;
        }
        {
            int row = tid >> 1, gi = tid & 1;
            int gid = (bn * 128 + row) * (INF / GS) + kt * 2 + gi;
            uint64_t lo, hi;
            load_group_bits(wq, gid, lo, hi);
            float nrm = wn[gid];
            float c2 = nrm * (2.0f / 7.0f), c1 = -nrm;
            bf16x8 o[4];
#pragma unroll
            for (int j = 0; j < 32; ++j) {
                uint32_t q = (j <= 20) ? (uint32_t)((lo >> (3 * j)) & 7)
                                       : (uint32_t)((hi >> (3 * j - 32)) & 7);
                o[j >> 3][j & 7] = (__bf16)((float)q * c2 + c1);
            }
            unsigned swz = (row & 7) << 4;
#pragma unroll
            for (int c4 = 0; c4 < 4; ++c4)
                *(bf16x8*)(lBraw + row * 128 + ((gi * 64 + c4 * 16) ^ swz)) = o[c4];
        }
        __syncthreads();

#pragma unroll
        for (int kk = 0; kk < 2; ++kk) {
            bf16x8 afr[4], bfr[4];
#pragma unroll
            for (int m = 0; m < 4; ++m)
                afr[m] = *(const bf16x8*)(lAraw + (aoff[m] ^ (kk * 64)));
#pragma unroll
            for (int n = 0; n < 4; ++n)
                bfr[n] = *(const bf16x8*)(lBraw + (boff[n] ^ (kk * 64)));
#pragma unroll
            for (int m = 0; m < 4; ++m)
#pragma unroll
                for (int n = 0; n < 4; ++n)
                    acc[m][n] = __builtin_amdgcn_mfma_f32_16x16x32_bf16(afr[m], bfr[n], acc[m][n], 0, 0, 0);
        }
    }

#pragma unroll
    for (int n = 0; n < 4; ++n) {
        int col = bn * 128 + wc * 64 + n * 16 + row16;
        float bv = bias[col];
#pragma unroll
        for (int m = 0; m < 4; ++m) {
            int rbase = bm * 128 + wr * 64 + m * 16 + kq * 4;
#pragma unroll
            for (int j = 0; j < 4; ++j)
                out[(size_t)(rbase + j) * OUTF + col] = acc[m][n][j] + bv;
        }
    }
}

extern "C" void kernel_launch(void* const* d_in, const int* in_sizes, int n_in,
                              void* d_out, int out_size, void* d_ws, size_t ws_size,
                              hipStream_t stream) {
    const float* x    = (const float*)d_in[0];
    const int*   wq   = (const int*)d_in[1];
    const float* wn   = (const float*)d_in[2];
    const float* bias = (const float*)d_in[3];
    float* out = (float*)d_out;

    const size_t xb_bytes = (size_t)MROWS * INF * 2;  // 32 MB
    const size_t wb_bytes = (size_t)OUTF * INF * 2;   // 32 MB
    if (ws_size >= xb_bytes + wb_bytes) {
        __bf16* xb = (__bf16*)d_ws;
        __bf16* wb = (__bf16*)((char*)d_ws + xb_bytes);
        prep_kernel<<<8192 + (OUTF * INF / GS) / 256, 256, 0, stream>>>(x, xb, wq, wn, wb);
        gemm8_kernel<<<(MROWS / 256) * (OUTF / 256), 512, 0, stream>>>(xb, wb, bias, out);
    } else {
        gemm_fb_kernel<<<dim3(OUTF / 128, MROWS / 128), 256, 0, stream>>>(x, wq, wn, bias, out);
    }
}